// Round 6
// baseline (220.461 us; speedup 1.0000x reference)
//
#include <hip/hip_runtime.h>
#include <hip/hip_bf16.h>

// ROUND 6 = DECOMPOSITION PROBE: identical kernels to round 5, but
// main_kernel is launched 3x back-to-back (idempotent). Per-launch cost
// k = (dur_us - 166.1) / 2. See decision tree in the analysis.

#define SEQ 512
#define HID 768
#define P2  46
#define MT  32              // rows per block
#define BLK 512             // 8 waves: 6 compute (2M x 3N), all 8 stage
#define NSTEP (HID / 32)    // 24 MFMA K-steps
#define QSTRIDE 48          // q row stride (padded)

typedef short bf16x8 __attribute__((ext_vector_type(8)));
typedef float f32x4  __attribute__((ext_vector_type(4)));

__device__ __forceinline__ unsigned short f2bf(float f) {
  union { float f; unsigned int u; } v; v.f = f;
  return (unsigned short)((v.u + 0x7FFFu + ((v.u >> 16) & 1u)) >> 16);
}

// hot-path cast: compiler lowers pairs to v_cvt_pk_bf16_f32 (RNE)
__device__ __forceinline__ unsigned short fcvt(float f) {
  __hip_bfloat16 x = __float2bfloat16(f);
  return *reinterpret_cast<unsigned short*>(&x);
}

// prep: q[b*48+p] = (h[b,i0,:]+h[b,i1,:]) . W[p,:] (exact fp32);
//       b==0 blocks also convert W row p -> bf16 workspace (+ zero pad rows)
__global__ __launch_bounds__(64) void prep_kernel(
    const float* __restrict__ h, const int* __restrict__ ids,
    const float* __restrict__ W, unsigned short* __restrict__ Wb,
    float* __restrict__ q) {
  int b = blockIdx.x, p = blockIdx.y, lane = threadIdx.x;
  const float* w = W + (size_t)p * HID;
  if (b == 0) {
    #pragma unroll
    for (int j = 0; j < HID / 64; ++j)
      Wb[p * HID + lane + j * 64] = f2bf(w[lane + j * 64]);
    if (p < 2) {                      // zero pad rows 46,47
      #pragma unroll
      for (int j = 0; j < HID / 64; ++j)
        Wb[(P2 + p) * HID + lane + j * 64] = 0;
    }
  }
  int i0 = ids[b * 2 + 0], i1 = ids[b * 2 + 1];
  const float* r0 = h + ((size_t)b * SEQ + i0) * HID;
  const float* r1 = h + ((size_t)b * SEQ + i1) * HID;
  float acc = 0.f;
  #pragma unroll
  for (int j = 0; j < HID / 64; ++j) {
    int k = lane + j * 64;
    acc += (r0[k] + r1[k]) * w[k];
  }
  #pragma unroll
  for (int off = 32; off > 0; off >>= 1) acc += __shfl_down(acc, off, 64);
  if (lane == 0) q[b * QSTRIDE + p] = acc;
}

// main: block stages its 32 rows (96 KB CONTIGUOUS, 1 KB/wave-instr linear)
// into swizzled bf16 LDS; 6 waves then each compute a full 16-row x 16-col
// x K=768 MFMA strip. One barrier, no K-split, W frags from L2-resident Wb.
__global__ __launch_bounds__(BLK, 4) void main_kernel(
    const float* __restrict__ h, const int* __restrict__ mask,
    const unsigned short* __restrict__ Wb, const float* __restrict__ bias,
    const float* __restrict__ q, float* __restrict__ out) {
  // [32 rows][96 chunks of 16B]; chunk c of row r stored at (c&~7)|((c^r)&7)
  __shared__ __align__(16) unsigned short hA[MT][HID];   // 48 KB

  const int tid  = threadIdx.x;
  const int lane = tid & 63, wv = tid >> 6;
  const int mr = lane & 15, qd = lane >> 4;
  const int row0 = blockIdx.x * MT;
  const int b    = row0 >> 9;                 // SEQ = 512

  // ---- stage: linear read of the block's 96 KB, cvt to bf16, swizzled write
  const float* hblk = h + (size_t)row0 * HID;
  #pragma unroll
  for (int i = 0; i < 12; ++i) {
    int g = i * BLK + tid;                    // float4 index, lane-consecutive
    float4 v = *(const float4*)(hblk + ((size_t)g << 2));
    int r  = g / 192;                         // row (192 float4 per row)
    int f  = g - r * 192;
    int c  = f >> 1, hc = f & 1;              // 16B chunk 0..95, half
    int cs = (c & 0x78) | ((c ^ r) & 7);
    ushort4 u;
    u.x = fcvt(v.x); u.y = fcvt(v.y); u.z = fcvt(v.z); u.w = fcvt(v.w);
    *(ushort4*)&hA[r][(cs << 3) + (hc << 2)] = u;
  }
  __syncthreads();

  if (wv >= 6) return;                        // 2 waves done (staging only)
  const int wm = wv & 1, nt = wv >> 1;        // 2 M-groups x 3 N-tiles

  const int rloc = (wm << 4) + mr;            // local h row for B-frag
  const unsigned short* wbp = Wb + (size_t)((nt << 4) + mr) * HID + (qd << 3);

  // issue epilogue scalars early (latency hides under K-loop)
  const int grow = row0 + rloc;
  const int mk   = mask[grow];
  const int p0   = (nt << 4) + (qd << 2);
  const float* qrow = q + b * QSTRIDE;
  float bv[4], qv[4];
  #pragma unroll
  for (int i = 0; i < 4; ++i) {
    bv[i] = (p0 + i < P2) ? bias[p0 + i] : 0.f;
    qv[i] = qrow[p0 + i];                     // padded row in workspace
  }

  f32x4 acc = f32x4{0.f, 0.f, 0.f, 0.f};
  #pragma unroll
  for (int s = 0; s < NSTEP; ++s) {
    int c  = (s << 2) + qd;
    int cs = (c & 0x78) | ((c ^ (rloc & 7)) & 7);
    bf16x8 a  = *(const bf16x8*)&hA[rloc][cs << 3];        // B-frag (h)
    bf16x8 wf = *(const bf16x8*)(wbp + (s << 5));          // A-frag (W, L2)
    acc = __builtin_amdgcn_mfma_f32_16x16x32_bf16(wf, a, acc, 0, 0, 0);
  }

  // ---- epilogue: D row = p (qd*4+i), D col = seq row (mr) ----
  float* orow = out + (size_t)grow * P2;
  float o[4];
  #pragma unroll
  for (int i = 0; i < 4; ++i) {
    float x = acc[i] + bv[i] + (mk ? qv[i] : 0.f);
    float sg = 1.f / (1.f + __expf(-x));
    sg *= sg; sg *= sg;                       // sigmoid^4
    o[i] = sg;
  }
  if (p0 + 1 < P2) *(float2*)(orow + p0)     = make_float2(o[0], o[1]);
  if (p0 + 3 < P2) *(float2*)(orow + p0 + 2) = make_float2(o[2], o[3]);
}

extern "C" void kernel_launch(void* const* d_in, const int* in_sizes, int n_in,
                              void* d_out, int out_size, void* d_ws, size_t ws_size,
                              hipStream_t stream) {
  const float* h    = (const float*)d_in[0];   // [64,512,768] fp32
  const int*   ids  = (const int*)d_in[1];     // [64,2]
  const int*   mask = (const int*)d_in[2];     // [64,512]
  const float* W    = (const float*)d_in[3];   // [46,768]
  const float* bias = (const float*)d_in[4];   // [46]
  float* out = (float*)d_out;                  // [64,512,46] fp32

  // workspace: Wb bf16 [48][768] (73728 B), then q fp32 [64][48]
  unsigned short* Wb = (unsigned short*)d_ws;
  float* q = (float*)((char*)d_ws + 48 * HID * sizeof(unsigned short));

  prep_kernel<<<dim3(64, P2), 64, 0, stream>>>(h, ids, W, Wb, q);
  // PROBE: 3x identical launches; extra two exist only to expose per-launch
  // cost in dur_us: k_main = (dur_us - 166.1) / 2.
  main_kernel<<<dim3((64 * SEQ) / MT), BLK, 0, stream>>>(h, mask, Wb, bias, q, out);
  main_kernel<<<dim3((64 * SEQ) / MT), BLK, 0, stream>>>(h, mask, Wb, bias, q, out);
  main_kernel<<<dim3((64 * SEQ) / MT), BLK, 0, stream>>>(h, mask, Wb, bias, q, out);
}

// Round 7
// 192.586 us; speedup vs baseline: 1.1447x; 1.1447x over previous
//
#include <hip/hip_runtime.h>
#include <hip/hip_bf16.h>

#define SEQ 512
#define HID 768
#define P2  46
#define MT  32              // rows per block
#define BLK 512             // 8 waves: 6 MFMA (2M x 3N), 2 compute q; all 8 stage
#define NSTEP (HID / 32)    // 24 MFMA K-steps

typedef short bf16x8 __attribute__((ext_vector_type(8)));
typedef float f32x4  __attribute__((ext_vector_type(4)));

// packed-pair friendly cast: lowers to v_cvt_pk_bf16_f32 (RNE)
__device__ __forceinline__ unsigned short fcvt(float f) {
  __hip_bfloat16 x = __float2bfloat16(f);
  return *reinterpret_cast<unsigned short*>(&x);
}

// Single fused kernel.
//  stage : all 8 waves, division-free linear read (1 KB/wave-instr contiguous),
//          cvt to bf16, XOR-swizzled LDS write.  barrier.
//  waves 0-5: full 16-row x 16-col x K=768 MFMA strip; W fp32 from L2 + cvt.
//  waves 6-7: q[b,p] = (h[b,i0,:]+h[b,i1,:]).W[p,:] exact fp32 -> LDS (overlapped).
//  barrier.  fused epilogue.
__global__ __launch_bounds__(BLK, 4) void fused_kernel(
    const float* __restrict__ h, const int* __restrict__ ids,
    const int* __restrict__ mask, const float* __restrict__ W,
    const float* __restrict__ bias, float* __restrict__ out) {
  // [32 rows][96 chunks of 16B]; chunk c of row r stored at (c&~7)|((c^r)&7)
  __shared__ __align__(16) unsigned short hA[MT][HID];   // 48 KB
  __shared__ __align__(16) float q_s[48];

  const int tid  = threadIdx.x;
  const int lane = tid & 63, wv = tid >> 6;
  const int mr = lane & 15, qd = lane >> 4;
  const int row0 = blockIdx.x * MT;
  const int b    = row0 >> 9;                 // SEQ = 512

  // ---- stage: division-free. wave wv owns rows 4wv..4wv+3 (3 iters/row) ----
  const float* hblk = h + (size_t)row0 * HID;
  #pragma unroll
  for (int i = 0; i < 12; ++i) {
    const int r = (wv << 2) + (i / 3);              // i/3 folds to a constant
    const int f = ((i % 3) << 6) + lane;            // float4 within row
    float4 v = *(const float4*)(hblk + ((size_t)(r * 192 + f) << 2));
    int c  = f >> 1, hc = f & 1;                    // 16B chunk, half
    int cs = (c & 0x78) | ((c ^ r) & 7);
    ushort4 u;
    u.x = fcvt(v.x); u.y = fcvt(v.y); u.z = fcvt(v.z); u.w = fcvt(v.w);
    *(ushort4*)&hA[r][(cs << 3) + (hc << 2)] = u;
  }
  __syncthreads();                                  // hA ready

  f32x4 acc = f32x4{0.f, 0.f, 0.f, 0.f};
  int nt = 0;

  if (wv < 6) {
    // ---- MFMA strip: A = W row (fp32 from L2, cvt), B = h frag from LDS ----
    const int wm = wv & 1;  nt = wv >> 1;           // 2 M-groups x 3 N-tiles
    const int rloc = (wm << 4) + mr;                // local h row
    int wrow = (nt << 4) + mr;
    if (wrow > P2 - 1) wrow = P2 - 1;               // clamp: no OOB read of W
    const float* wp = W + (size_t)wrow * HID + (qd << 3);

    #pragma unroll
    for (int s = 0; s < NSTEP; ++s) {
      int c  = (s << 2) + qd;
      int cs = (c & 0x78) | ((c ^ (rloc & 7)) & 7);
      bf16x8 a = *(const bf16x8*)&hA[rloc][cs << 3];       // h frag
      float4 w0 = *(const float4*)(wp + (s << 5));
      float4 w1 = *(const float4*)(wp + (s << 5) + 4);
      bf16x8 wf = { (short)fcvt(w0.x), (short)fcvt(w0.y),
                    (short)fcvt(w0.z), (short)fcvt(w0.w),
                    (short)fcvt(w1.x), (short)fcvt(w1.y),
                    (short)fcvt(w1.z), (short)fcvt(w1.w) };
      acc = __builtin_amdgcn_mfma_f32_16x16x32_bf16(wf, a, acc, 0, 0, 0);
    }
  } else {
    // ---- q compute on otherwise-idle waves (overlaps the MFMA phase) ----
    const int i0 = ids[b * 2 + 0], i1 = ids[b * 2 + 1];
    const float* r0p = h + ((size_t)b * SEQ + i0) * HID;
    const float* r1p = h + ((size_t)b * SEQ + i1) * HID;
    float hs[12];
    #pragma unroll
    for (int j = 0; j < 12; ++j) {
      int k = lane + (j << 6);
      hs[j] = r0p[k] + r1p[k];
    }
    if (wv == 6 && lane == 0) { q_s[46] = 0.f; q_s[47] = 0.f; }
    const int pbase = (wv - 6) * 23;
    for (int j = 0; j < 23; ++j) {
      const float* wrow = W + (size_t)(pbase + j) * HID;
      float a = 0.f;
      #pragma unroll
      for (int k = 0; k < 12; ++k)
        a += hs[k] * wrow[lane + (k << 6)];
      #pragma unroll
      for (int off = 32; off > 0; off >>= 1) a += __shfl_xor(a, off, 64);
      if (lane == 0) q_s[pbase + j] = a;
    }
  }
  __syncthreads();                                  // q_s ready
  if (wv >= 6) return;

  // ---- epilogue: D row = p (qd*4+i), D col = seq row (mr) ----
  const int rloc = ((wv & 1) << 4) + mr;
  const int grow = row0 + rloc;
  const int mk   = mask[grow];
  const int p0   = (nt << 4) + (qd << 2);
  float4 qv = *(const float4*)&q_s[p0];             // p0 is 16B-aligned
  float* orow = out + (size_t)grow * P2;
  float o[4];
  #pragma unroll
  for (int i = 0; i < 4; ++i) {
    float bv = (p0 + i < P2) ? bias[p0 + i] : 0.f;
    float x = acc[i] + bv + (mk ? ((const float*)&qv)[i] : 0.f);
    float sg = 1.f / (1.f + __expf(-x));
    sg *= sg; sg *= sg;                             // sigmoid^4
    o[i] = sg;
  }
  if (p0 + 1 < P2) *(float2*)(orow + p0)     = make_float2(o[0], o[1]);
  if (p0 + 3 < P2) *(float2*)(orow + p0 + 2) = make_float2(o[2], o[3]);
}

extern "C" void kernel_launch(void* const* d_in, const int* in_sizes, int n_in,
                              void* d_out, int out_size, void* d_ws, size_t ws_size,
                              hipStream_t stream) {
  const float* h    = (const float*)d_in[0];   // [64,512,768] fp32
  const int*   ids  = (const int*)d_in[1];     // [64,2]
  const int*   mask = (const int*)d_in[2];     // [64,512]
  const float* W    = (const float*)d_in[3];   // [46,768]
  const float* bias = (const float*)d_in[4];   // [46]
  float* out = (float*)d_out;                  // [64,512,46] fp32

  fused_kernel<<<dim3((64 * SEQ) / MT), BLK, 0, stream>>>(h, ids, mask, W, bias, out);
}

// Round 8
// 164.463 us; speedup vs baseline: 1.3405x; 1.1710x over previous
//
#include <hip/hip_runtime.h>
#include <hip/hip_bf16.h>

#define SEQ 512
#define HID 768
#define P2  46
#define MT  16              // rows per block
#define BLK 256             // 4 waves: all issue DMA; waves 0-2 compute nt=0..2
#define NSTEP (HID / 32)    // 24 MFMA K-steps
#define QSTRIDE 48          // q row stride (padded)

typedef short bf16x8 __attribute__((ext_vector_type(8)));
typedef float f32x4  __attribute__((ext_vector_type(4)));

__device__ __forceinline__ unsigned short f2bf(float f) {
  union { float f; unsigned int u; } v; v.f = f;
  return (unsigned short)((v.u + 0x7FFFu + ((v.u >> 16) & 1u)) >> 16);
}

// packed-pair friendly cast: lowers to v_cvt_pk_bf16_f32 (RNE)
__device__ __forceinline__ unsigned short fcvt(float f) {
  __hip_bfloat16 x = __float2bfloat16(f);
  return *reinterpret_cast<unsigned short*>(&x);
}

__device__ __forceinline__ void async_ld16(const void* g, void* l) {
  // global -> LDS DMA, 16 B/lane; LDS dest = wave-uniform base + lane*16
  __builtin_amdgcn_global_load_lds(
      (const __attribute__((address_space(1))) unsigned int*)g,
      (__attribute__((address_space(3))) unsigned int*)l, 16, 0, 0);
}

// prep: q[b*48+p] = (h[b,i0,:]+h[b,i1,:]) . W[p,:] (exact fp32);
//       b==0 blocks also convert W row p -> bf16 workspace (+ zero pad rows)
//       (verbatim from round 6 — verified)
__global__ __launch_bounds__(64) void prep_kernel(
    const float* __restrict__ h, const int* __restrict__ ids,
    const float* __restrict__ W, unsigned short* __restrict__ Wb,
    float* __restrict__ q) {
  int b = blockIdx.x, p = blockIdx.y, lane = threadIdx.x;
  const float* w = W + (size_t)p * HID;
  if (b == 0) {
    #pragma unroll
    for (int j = 0; j < HID / 64; ++j)
      Wb[p * HID + lane + j * 64] = f2bf(w[lane + j * 64]);
    if (p < 2) {                      // zero pad rows 46,47
      #pragma unroll
      for (int j = 0; j < HID / 64; ++j)
        Wb[(P2 + p) * HID + lane + j * 64] = 0;
    }
  }
  int i0 = ids[b * 2 + 0], i1 = ids[b * 2 + 1];
  const float* r0 = h + ((size_t)b * SEQ + i0) * HID;
  const float* r1 = h + ((size_t)b * SEQ + i1) * HID;
  float acc = 0.f;
  #pragma unroll
  for (int j = 0; j < HID / 64; ++j) {
    int k = lane + j * 64;
    acc += (r0[k] + r1[k]) * w[k];
  }
  #pragma unroll
  for (int off = 32; off > 0; off >>= 1) acc += __shfl_down(acc, off, 64);
  if (lane == 0) q[b * QSTRIDE + p] = acc;
}

// main: h staged fp32 via global_load_lds (zero VALU/VGPR staging), source-side
// 32B-group XOR swizzle (LDS dest linear, read applies same XOR). W frags
// (bf16, L2) + epilogue scalars preloaded to regs BEFORE the single barrier.
__global__ __launch_bounds__(BLK, 3) void main_kernel(
    const float* __restrict__ h, const int* __restrict__ mask,
    const unsigned short* __restrict__ Wb, const float* __restrict__ bias,
    const float* __restrict__ q, float* __restrict__ out) {
  // fp32 tile [16 rows][768]; within a row, 32B group gg holds global group
  // (gg&~7)|((gg^row)&7)  (XOR involution, applied to DMA *source* address)
  __shared__ __align__(16) float hA[MT][HID];   // 49152 B -> 3 blocks/CU

  const int tid  = threadIdx.x;
  const int lane = tid & 63, wv = tid >> 6;
  const int mr = lane & 15, qd = lane >> 4;
  const int row0 = blockIdx.x * MT;
  const int b    = row0 >> 9;                 // SEQ = 512

  // ---- 1) issue 12 DMA instrs/wave (48 x 1KB = whole 48 KB tile) ----
  const float* hblk = h + (size_t)row0 * HID;
  #pragma unroll
  for (int j = 0; j < 12; ++j) {
    const int r   = (wv << 2) + j / 3;        // row 0..15 (folds per-iter)
    const int seg = j % 3;                    // 1KB segment of the 3KB row
    int c  = (seg << 6) + lane;               // 16B chunk within row, 0..191
    int gg = c >> 1;                          // 32B group 0..95
    int gs = (gg & ~7) | ((gg ^ r) & 7);      // swizzled source group
    const float* src = hblk + (size_t)r * HID + ((gs << 1) | (c & 1)) * 4;
    async_ld16(src, &hA[r][seg << 8]);        // dest wave-uniform, linear
  }

  // ---- 2) register preloads (overlap the DMA window), waves 0-2 only ----
  const int nt = wv;                          // n-tile 0..2
  bf16x8 wf[NSTEP];
  f32x4 acc = f32x4{0.f, 0.f, 0.f, 0.f};
  int mk = 0, p0 = 0, grow = 0;
  float bv[4], qv[4];
  if (wv < 3) {
    const unsigned short* wbp = Wb + (size_t)((nt << 4) + mr) * HID + (qd << 3);
    #pragma unroll
    for (int s = 0; s < NSTEP; ++s)
      wf[s] = *(const bf16x8*)(wbp + (s << 5));
    grow = row0 + mr;                         // this lane's seq row (D col=mr)
    mk   = mask[grow];
    p0   = (nt << 4) + (qd << 2);
    const float* qrow = q + b * QSTRIDE;
    #pragma unroll
    for (int i = 0; i < 4; ++i) {
      bv[i] = (p0 + i < P2) ? bias[p0 + i] : 0.f;
      qv[i] = qrow[p0 + i];                   // padded row in workspace
    }
  }

  __syncthreads();                            // drains DMAs (vmcnt 0) + sync
  if (wv >= 3) return;

  // ---- 3) K loop: pure LDS -> cvt_pk -> MFMA (no global dependency) ----
  #pragma unroll
  for (int s = 0; s < NSTEP; ++s) {
    int gg = (s << 2) + qd;
    int gs = (gg & ~7) | ((gg ^ mr) & 7);     // same XOR, row = mr
    const float* fp = &hA[mr][gs << 3];       // 32B group = 8 floats
    float4 a0 = *(const float4*)fp;
    float4 a1 = *(const float4*)(fp + 4);
    bf16x8 hb = { (short)fcvt(a0.x), (short)fcvt(a0.y),
                  (short)fcvt(a0.z), (short)fcvt(a0.w),
                  (short)fcvt(a1.x), (short)fcvt(a1.y),
                  (short)fcvt(a1.z), (short)fcvt(a1.w) };
    acc = __builtin_amdgcn_mfma_f32_16x16x32_bf16(wf[s], hb, acc, 0, 0, 0);
  }

  // ---- 4) epilogue: D row = p (qd*4+i), D col = seq row (mr) ----
  float* orow = out + (size_t)grow * P2;
  float o[4];
  #pragma unroll
  for (int i = 0; i < 4; ++i) {
    float x = acc[i] + bv[i] + (mk ? qv[i] : 0.f);
    float sg = 1.f / (1.f + __expf(-x));
    sg *= sg; sg *= sg;                       // sigmoid^4
    o[i] = sg;
  }
  if (p0 + 1 < P2) *(float2*)(orow + p0)     = make_float2(o[0], o[1]);
  if (p0 + 3 < P2) *(float2*)(orow + p0 + 2) = make_float2(o[2], o[3]);
}

extern "C" void kernel_launch(void* const* d_in, const int* in_sizes, int n_in,
                              void* d_out, int out_size, void* d_ws, size_t ws_size,
                              hipStream_t stream) {
  const float* h    = (const float*)d_in[0];   // [64,512,768] fp32
  const int*   ids  = (const int*)d_in[1];     // [64,2]
  const int*   mask = (const int*)d_in[2];     // [64,512]
  const float* W    = (const float*)d_in[3];   // [46,768]
  const float* bias = (const float*)d_in[4];   // [46]
  float* out = (float*)d_out;                  // [64,512,46] fp32

  // workspace: Wb bf16 [48][768] (73728 B), then q fp32 [64][48]
  unsigned short* Wb = (unsigned short*)d_ws;
  float* q = (float*)((char*)d_ws + 48 * HID * sizeof(unsigned short));

  prep_kernel<<<dim3(64, P2), 64, 0, stream>>>(h, ids, W, Wb, q);
  main_kernel<<<dim3((64 * SEQ) / MT), BLK, 0, stream>>>(h, mask, Wb, bias, q, out);
}